// Round 9
// baseline (216.042 us; speedup 1.0000x reference)
//
#include <hip/hip_runtime.h>

#define H_DIM 1024
#define I_DIM 512
#define NE 8
#define SI_DIM 1024
#define NT 2048

typedef __bf16 bf16;
typedef __bf16 bf16x4 __attribute__((ext_vector_type(4)));
typedef __bf16 bf16x8 __attribute__((ext_vector_type(8)));
typedef float f32x4 __attribute__((ext_vector_type(4)));

// ---- bf16 weight buffer layout (elements), R4-verified interleave ----
// W_GU: per expert, 1024 rows interleaved by 16 (gate16,up16,...), K=H
// W_DN: per expert, H rows x I(K); W_SGU: shared interleaved; W_SDN: shared down
#define W_GU 0ull
#define W_DN 8388608ull
#define W_SGU 12582912ull
#define W_SDN 14680064ull
#define W_TOT 15728640ull

#define NWB 15360  // weight-convert blocks (W_TOT/1024)
#define NRB 512    // router blocks (router also writes xb)

// ---- workspace (bytes, 16B aligned). lists = NE*NT ints (R8 fix). ----
#define OFF_CNT 0
#define OFF_WM 64
#define OFF_TOPI 1024
#define OFF_TOPW (OFF_TOPI + NT * 8)
#define OFF_LISTS (OFF_TOPW + NT * 8)
#define OFF_WB (OFF_LISTS + NE * NT * 4)                  // bf16[W_TOT]
#define OFF_XB (OFF_WB + (size_t)W_TOT * 2)               // bf16[NT][H]
#define OFF_ACTE (OFF_XB + (size_t)NT * H_DIM * 2)        // bf16[NE][NT][I]
#define OFF_ACTS (OFF_ACTE + (size_t)NE * NT * I_DIM * 2) // bf16[NT][SI]

__device__ __forceinline__ bf16x4 cvt4(f32x4 v) {
  bf16x4 r;
  r.x = (bf16)v.x; r.y = (bf16)v.y; r.z = (bf16)v.z; r.w = (bf16)v.w;
  return r;
}

__device__ __forceinline__ void glds16(const bf16* g, bf16* l) {
  __builtin_amdgcn_global_load_lds(
      (const __attribute__((address_space(1))) unsigned int*)g,
      (__attribute__((address_space(3))) unsigned int*)l, 16, 0, 0);
}

// ---- prep: weight convert (interleaved, R4-verified) + router(+x-convert) ----
__global__ __launch_bounds__(256) void prep_kernel(
    const float* __restrict__ x, const float* __restrict__ gw,
    const float* __restrict__ lb, const float* __restrict__ eg,
    const float* __restrict__ eu, const float* __restrict__ ed,
    const float* __restrict__ sg, const float* __restrict__ su,
    const float* __restrict__ sd, bf16* __restrict__ wb,
    bf16* __restrict__ xb, int2* __restrict__ topi,
    float2* __restrict__ topw) {
  const int bx = blockIdx.x;
  const int tid = threadIdx.x;
  if (bx < NWB) {
    size_t i = ((size_t)bx * 256 + tid) * 4;
    const float* src;
    if (i < W_DN) {
      size_t z = i >> 20;
      int rem = (int)(i & ((1u << 20) - 1));
      int rp = rem >> 10, k = rem & 1023;
      int b = rp >> 4;
      int sr = ((b >> 1) << 4) | (rp & 15);
      src = ((b & 1) ? eu : eg) + (z << 19) + ((size_t)sr << 10) + k;
    } else if (i < W_SGU) {
      src = ed + (i - W_DN);
    } else if (i < W_SDN) {
      int rem = (int)(i - W_SGU);
      int rp = rem >> 10, k = rem & 1023;
      int b = rp >> 4;
      int sr = ((b >> 1) << 4) | (rp & 15);
      src = ((b & 1) ? su : sg) + ((size_t)sr << 10) + k;
    } else {
      src = sd + (i - W_SDN);
    }
    *(bf16x4*)(wb + i) = cvt4(*(const f32x4*)src);
  } else {
    const int lane = tid & 63;
    const int t = (bx - NWB) * 4 + (tid >> 6);
    const float* xr = x + (size_t)t * H_DIM;
    bf16* xw = xb + (size_t)t * H_DIM;
    float s[NE];
#pragma unroll
    for (int e = 0; e < NE; e++) s[e] = 0.f;
#pragma unroll
    for (int k0 = 0; k0 < H_DIM; k0 += 256) {
      f32x4 xv = *(const f32x4*)(xr + k0 + lane * 4);
      *(bf16x4*)(xw + k0 + lane * 4) = cvt4(xv);
#pragma unroll
      for (int e = 0; e < NE; e++) {
        f32x4 gv = *(const f32x4*)(gw + e * H_DIM + k0 + lane * 4);
        s[e] += xv.x * gv.x + xv.y * gv.y + xv.z * gv.z + xv.w * gv.w;
      }
    }
#pragma unroll
    for (int e = 0; e < NE; e++) {
      float v = s[e];
#pragma unroll
      for (int off = 32; off > 0; off >>= 1) v += __shfl_xor(v, off);
      s[e] = v;
    }
    if (lane == 0) {
      float sc[NE];
#pragma unroll
      for (int e = 0; e < NE; e++) sc[e] = 1.f / (1.f + expf(-(s[e] + lb[e])));
      int i1 = 0;
#pragma unroll
      for (int e = 1; e < NE; e++)
        if (sc[e] > sc[i1]) i1 = e;  // ties -> lowest index (lax.top_k)
      int i2 = -1;
#pragma unroll
      for (int e = 0; e < NE; e++) {
        if (e == i1) continue;
        if (i2 < 0 || sc[e] > sc[i2]) i2 = e;
      }
      float w1 = sc[i1], w2 = sc[i2];
      float inv = 1.f / (w1 + w2 + 1e-8f);
      topi[t] = make_int2(i1, i2);
      topw[t] = make_float2(w1 * inv, w2 * inv);
    }
  }
}

// ---- build: 8 blocks (one per expert), fixed slot regions, no atomics ----
__global__ __launch_bounds__(256) void build_kernel(
    const int2* __restrict__ topi, const float2* __restrict__ topw,
    int* __restrict__ cnt, float* __restrict__ wm, int* __restrict__ lists) {
  const int e = blockIdx.x;
  const int wave = threadIdx.x >> 6, lane = threadIdx.x & 63;
  __shared__ int wc[4];
  __shared__ float wf[4];
  const int tbeg = wave * (NT / 4), tend = tbeg + NT / 4;

  int c = 0;
  float wa = 0.f;
  for (int t0 = tbeg; t0 < tend; t0 += 64) {
    int2 ti = topi[t0 + lane];
    float2 tw = topw[t0 + lane];
    bool hit = (ti.x == e) || (ti.y == e);
    float w = (ti.x == e) ? tw.x : ((ti.y == e) ? tw.y : 0.f);
    c += __popcll(__ballot(hit));
#pragma unroll
    for (int off = 32; off > 0; off >>= 1) w += __shfl_xor(w, off);
    wa += w;
  }
  if (lane == 0) { wc[wave] = c; wf[wave] = wa; }
  __syncthreads();
  int pos = 0;
  for (int w = 0; w < wave; w++) pos += wc[w];
  for (int t0 = tbeg; t0 < tend; t0 += 64) {
    int t = t0 + lane;
    int2 ti = topi[t];
    bool hit = (ti.x == e) || (ti.y == e);
    unsigned long long m = __ballot(hit);
    int pre = __popcll(m & ((1ull << lane) - 1ull));
    if (hit) lists[e * NT + pos + pre] = t;
    pos += __popcll(m);
  }
  if (threadIdx.x == 0) {
    int ctot = wc[0] + wc[1] + wc[2] + wc[3];
    cnt[e] = ctot;
    wm[e] = (wf[0] + wf[1] + wf[2] + wf[3]) / (float)(ctot > 0 ? ctot : 1);
  }
}

// ---- gate+up GEMM: glds16 both sides from bf16, XOR swizzle (0 conflicts),
// interleaved B columns; epilogue silu(g)*u -> bf16 act.
// grid (16 rt, 16 ct, 9): x=rt fastest so consecutive blocks share the B tile.
__global__ __launch_bounds__(256, 2) void gemm_gu(
    const bf16* __restrict__ wb, const bf16* __restrict__ xb,
    const int* __restrict__ cnt, const int* __restrict__ lists,
    bf16* __restrict__ act_e, bf16* __restrict__ act_s) {
  const int z = blockIdx.z, rt = blockIdx.x, ct = blockIdx.y;
  const int tid = threadIdx.x;
  __shared__ int rows_s[128];
  __shared__ __align__(16) bf16 As[128 * 64];
  __shared__ __align__(16) bf16 Bs[128 * 64];
  int mrem, ldc;
  bf16* Cb;
  const bf16* Bb;
  if (z < NE) {
    if (ct >= 8) return;
    int c = cnt[z];
    if (rt * 128 >= c) return;
    mrem = c - rt * 128;
    if (tid < 128)
      rows_s[tid] = lists[z * NT + rt * 128 + (tid < mrem ? tid : mrem - 1)];
    Bb = wb + W_GU + ((size_t)z << 20) + (size_t)ct * 128 * H_DIM;
    Cb = act_e + ((size_t)z * NT + rt * 128) * I_DIM;
    ldc = I_DIM;
  } else {
    mrem = 128;
    if (tid < 128) rows_s[tid] = rt * 128 + tid;
    Bb = wb + W_SGU + (size_t)ct * 128 * H_DIM;
    Cb = act_s + (size_t)rt * 128 * SI_DIM;
    ldc = SI_DIM;
  }
  __syncthreads();

  const int lane = tid & 63, wave = tid >> 6;
  const int mw = (wave >> 1) * 64, nw = (wave & 1) * 64;
  const int l15 = lane & 15, quad = lane >> 4;
  const int srow = tid >> 3;   // 0..31
  const int cch = tid & 7;     // 16B chunk id
  const int p8 = cch * 8;
  const int sx = (l15 & 7) * 8;

  const bf16 *ap[4], *bp[4];
  int lo[4];
#pragma unroll
  for (int r = 0; r < 4; r++) {
    int R = srow + r * 32;
    int gs = (cch ^ (R & 7)) * 8;  // swizzled source chunk
    ap[r] = xb + (size_t)rows_s[R] * H_DIM + gs;
    bp[r] = Bb + (size_t)R * H_DIM + gs;
    lo[r] = R * 64 + p8;  // lane-ordered LDS dest (HW: base + lane*16)
  }

  f32x4 acc[4][4] = {};
  for (int k0 = 0; k0 < H_DIM; k0 += 64) {
#pragma unroll
    for (int r = 0; r < 4; r++) glds16(ap[r] + k0, &As[lo[r]]);
#pragma unroll
    for (int r = 0; r < 4; r++) glds16(bp[r] + k0, &Bs[lo[r]]);
    __syncthreads();
#pragma unroll
    for (int kk = 0; kk < 2; kk++) {
      const int ko = (kk * 4 + quad) * 8;
      bf16x8 av[4], bv[4];
#pragma unroll
      for (int i = 0; i < 4; i++) {
        av[i] = *(const bf16x8*)&As[(mw + i * 16 + l15) * 64 + (ko ^ sx)];
        bv[i] = *(const bf16x8*)&Bs[(nw + i * 16 + l15) * 64 + (ko ^ sx)];
      }
#pragma unroll
      for (int i = 0; i < 4; i++)
#pragma unroll
        for (int j = 0; j < 4; j++)
          acc[i][j] = __builtin_amdgcn_mfma_f32_16x16x32_bf16(av[i], bv[j], acc[i][j], 0, 0, 0);
    }
    __syncthreads();
  }

  // j even = gate, j odd = up (adjacent 16-col groups, same lane/reg)
#pragma unroll
  for (int i = 0; i < 4; i++) {
#pragma unroll
    for (int rg = 0; rg < 4; rg++) {
      int rl = mw + i * 16 + quad * 4 + rg;
      if (rl < mrem) {
#pragma unroll
        for (int jp = 0; jp < 2; jp++) {
          float g = acc[i][jp * 2][rg];
          float u = acc[i][jp * 2 + 1][rg];
          int c = ct * 64 + (nw >> 1) + jp * 16 + l15;
          Cb[(size_t)rl * ldc + c] = (bf16)((g / (1.f + __expf(-g))) * u);
        }
      }
    }
  }
}

// ---- down GEMM: glds16 both sides, swizzled; atomicAdd(out, wm*y).
// grid (16 rt, 8 ct, 9): rt fastest for B-tile L2 reuse.
__global__ __launch_bounds__(256, 2) void gemm_down(
    const bf16* __restrict__ wb, const bf16* __restrict__ act_e,
    const bf16* __restrict__ act_s, const int* __restrict__ cnt,
    const float* __restrict__ wm, const int* __restrict__ lists,
    float* __restrict__ out) {
  const int z = blockIdx.z, rt = blockIdx.x, ct = blockIdx.y;
  const int tid = threadIdx.x;
  __shared__ int rows_s[128];
  __shared__ __align__(16) bf16 As[128 * 64];
  __shared__ __align__(16) bf16 Bs[128 * 64];
  int K, mrem;
  const bf16 *Ab, *Bb;
  if (z < NE) {
    int c = cnt[z];
    if (rt * 128 >= c) return;
    mrem = c - rt * 128;
    if (tid < 128)
      rows_s[tid] = lists[z * NT + rt * 128 + (tid < mrem ? tid : mrem - 1)];
    Ab = act_e + ((size_t)z * NT + rt * 128) * I_DIM;
    K = I_DIM;
    Bb = wb + W_DN + ((size_t)z << 19) + (size_t)ct * 128 * I_DIM;
  } else {
    mrem = 128;
    if (tid < 128) rows_s[tid] = rt * 128 + tid;
    Ab = act_s + (size_t)rt * 128 * SI_DIM;
    K = SI_DIM;
    Bb = wb + W_SDN + (size_t)ct * 128 * SI_DIM;
  }
  __syncthreads();

  const int lane = tid & 63, wave = tid >> 6;
  const int mw = (wave >> 1) * 64, nw = (wave & 1) * 64;
  const int l15 = lane & 15, quad = lane >> 4;
  const int srow = tid >> 3;
  const int cch = tid & 7;
  const int p8 = cch * 8;
  const int sx = (l15 & 7) * 8;

  const bf16 *ap[4], *bp[4];
  int lo[4];
#pragma unroll
  for (int r = 0; r < 4; r++) {
    int R = srow + r * 32;
    int gs = (cch ^ (R & 7)) * 8;
    ap[r] = Ab + (size_t)R * K + gs;
    bp[r] = Bb + (size_t)R * K + gs;
    lo[r] = R * 64 + p8;
  }

  f32x4 acc[4][4] = {};
  for (int k0 = 0; k0 < K; k0 += 64) {
#pragma unroll
    for (int r = 0; r < 4; r++) glds16(ap[r] + k0, &As[lo[r]]);
#pragma unroll
    for (int r = 0; r < 4; r++) glds16(bp[r] + k0, &Bs[lo[r]]);
    __syncthreads();
#pragma unroll
    for (int kk = 0; kk < 2; kk++) {
      const int ko = (kk * 4 + quad) * 8;
      bf16x8 av[4], bv[4];
#pragma unroll
      for (int i = 0; i < 4; i++) {
        av[i] = *(const bf16x8*)&As[(mw + i * 16 + l15) * 64 + (ko ^ sx)];
        bv[i] = *(const bf16x8*)&Bs[(nw + i * 16 + l15) * 64 + (ko ^ sx)];
      }
#pragma unroll
      for (int i = 0; i < 4; i++)
#pragma unroll
        for (int j = 0; j < 4; j++)
          acc[i][j] = __builtin_amdgcn_mfma_f32_16x16x32_bf16(av[i], bv[j], acc[i][j], 0, 0, 0);
    }
    __syncthreads();
  }

  const float wsc = (z < NE) ? wm[z] : 1.f;
#pragma unroll
  for (int i = 0; i < 4; i++) {
#pragma unroll
    for (int rg = 0; rg < 4; rg++) {
      int rl = mw + i * 16 + quad * 4 + rg;
      if (rl < mrem) {
        int t = rows_s[rl];
        float* orow = out + (size_t)t * H_DIM + ct * 128 + nw;
#pragma unroll
        for (int j = 0; j < 4; j++)
          atomicAdd(&orow[j * 16 + l15], wsc * acc[i][j][rg]);
      }
    }
  }
}

extern "C" void kernel_launch(void* const* d_in, const int* in_sizes, int n_in,
                              void* d_out, int out_size, void* d_ws,
                              size_t ws_size, hipStream_t stream) {
  (void)in_sizes; (void)n_in; (void)out_size; (void)ws_size;
  const float* x  = (const float*)d_in[0];
  const float* gw = (const float*)d_in[1];
  const float* lb = (const float*)d_in[2];
  const float* eg = (const float*)d_in[3];
  const float* eu = (const float*)d_in[4];
  const float* ed = (const float*)d_in[5];
  const float* sg = (const float*)d_in[6];
  const float* su = (const float*)d_in[7];
  const float* sd = (const float*)d_in[8];
  float* out = (float*)d_out;
  char* ws = (char*)d_ws;

  int* cnt     = (int*)(ws + OFF_CNT);
  float* wm    = (float*)(ws + OFF_WM);
  int2* topi   = (int2*)(ws + OFF_TOPI);
  float2* topw = (float2*)(ws + OFF_TOPW);
  int* lists   = (int*)(ws + OFF_LISTS);
  bf16* wb     = (bf16*)(ws + OFF_WB);
  bf16* xb     = (bf16*)(ws + OFF_XB);
  bf16* act_e  = (bf16*)(ws + OFF_ACTE);
  bf16* act_s  = (bf16*)(ws + OFF_ACTS);

  hipMemsetAsync(d_out, 0, (size_t)NT * H_DIM * sizeof(float), stream);
  prep_kernel<<<NWB + NRB, 256, 0, stream>>>(x, gw, lb, eg, eu, ed, sg, su, sd,
                                             wb, xb, topi, topw);
  build_kernel<<<NE, 256, 0, stream>>>(topi, topw, cnt, wm, lists);
  gemm_gu<<<dim3(16, 16, 9), 256, 0, stream>>>(wb, xb, cnt, lists, act_e,
                                               act_s);
  gemm_down<<<dim3(16, 8, 9), 256, 0, stream>>>(wb, act_e, act_s, cnt, wm,
                                                lists, out);
}

// Round 10
// 201.851 us; speedup vs baseline: 1.0703x; 1.0703x over previous
//
#include <hip/hip_runtime.h>

#define H_DIM 1024
#define I_DIM 512
#define NE 8
#define SI_DIM 1024
#define NT 2048

typedef __bf16 bf16;
typedef __bf16 bf16x4 __attribute__((ext_vector_type(4)));
typedef __bf16 bf16x8 __attribute__((ext_vector_type(8)));
typedef float f32x4 __attribute__((ext_vector_type(4)));

// ---- bf16 weight buffer layout (elements), R4-verified interleave ----
#define W_GU 0ull
#define W_DN 8388608ull
#define W_SGU 12582912ull
#define W_SDN 14680064ull
#define W_TOT 15728640ull

#define NWB 15360  // weight-convert blocks (W_TOT/1024)
#define NRB 512    // router blocks (router also writes xb)

// ---- workspace (bytes, 16B aligned). lists = NE*NT ints (R8 fix). ----
#define OFF_CNT 0
#define OFF_WM 64
#define OFF_TOPI 1024
#define OFF_TOPW (OFF_TOPI + NT * 8)
#define OFF_LISTS (OFF_TOPW + NT * 8)
#define OFF_WB (OFF_LISTS + NE * NT * 4)                  // bf16[W_TOT]
#define OFF_XB (OFF_WB + (size_t)W_TOT * 2)               // bf16[NT][H]
#define OFF_ACTE (OFF_XB + (size_t)NT * H_DIM * 2)        // bf16[NE][NT][I]
#define OFF_ACTS (OFF_ACTE + (size_t)NE * NT * I_DIM * 2) // bf16[NT][SI]

__device__ __forceinline__ bf16x4 cvt4(f32x4 v) {
  bf16x4 r;
  r.x = (bf16)v.x; r.y = (bf16)v.y; r.z = (bf16)v.z; r.w = (bf16)v.w;
  return r;
}

__device__ __forceinline__ void glds16(const bf16* g, bf16* l) {
  __builtin_amdgcn_global_load_lds(
      (const __attribute__((address_space(1))) unsigned int*)g,
      (__attribute__((address_space(3))) unsigned int*)l, 16, 0, 0);
}

// ---- prep: weight convert (interleaved) + router(+x-convert). R9-proven. ----
__global__ __launch_bounds__(256) void prep_kernel(
    const float* __restrict__ x, const float* __restrict__ gw,
    const float* __restrict__ lb, const float* __restrict__ eg,
    const float* __restrict__ eu, const float* __restrict__ ed,
    const float* __restrict__ sg, const float* __restrict__ su,
    const float* __restrict__ sd, bf16* __restrict__ wb,
    bf16* __restrict__ xb, int2* __restrict__ topi,
    float2* __restrict__ topw) {
  const int bx = blockIdx.x;
  const int tid = threadIdx.x;
  if (bx < NWB) {
    size_t i = ((size_t)bx * 256 + tid) * 4;
    const float* src;
    if (i < W_DN) {
      size_t z = i >> 20;
      int rem = (int)(i & ((1u << 20) - 1));
      int rp = rem >> 10, k = rem & 1023;
      int b = rp >> 4;
      int sr = ((b >> 1) << 4) | (rp & 15);
      src = ((b & 1) ? eu : eg) + (z << 19) + ((size_t)sr << 10) + k;
    } else if (i < W_SGU) {
      src = ed + (i - W_DN);
    } else if (i < W_SDN) {
      int rem = (int)(i - W_SGU);
      int rp = rem >> 10, k = rem & 1023;
      int b = rp >> 4;
      int sr = ((b >> 1) << 4) | (rp & 15);
      src = ((b & 1) ? su : sg) + ((size_t)sr << 10) + k;
    } else {
      src = sd + (i - W_SDN);
    }
    *(bf16x4*)(wb + i) = cvt4(*(const f32x4*)src);
  } else {
    const int lane = tid & 63;
    const int t = (bx - NWB) * 4 + (tid >> 6);
    const float* xr = x + (size_t)t * H_DIM;
    bf16* xw = xb + (size_t)t * H_DIM;
    float s[NE];
#pragma unroll
    for (int e = 0; e < NE; e++) s[e] = 0.f;
#pragma unroll
    for (int k0 = 0; k0 < H_DIM; k0 += 256) {
      f32x4 xv = *(const f32x4*)(xr + k0 + lane * 4);
      *(bf16x4*)(xw + k0 + lane * 4) = cvt4(xv);
#pragma unroll
      for (int e = 0; e < NE; e++) {
        f32x4 gv = *(const f32x4*)(gw + e * H_DIM + k0 + lane * 4);
        s[e] += xv.x * gv.x + xv.y * gv.y + xv.z * gv.z + xv.w * gv.w;
      }
    }
#pragma unroll
    for (int e = 0; e < NE; e++) {
      float v = s[e];
#pragma unroll
      for (int off = 32; off > 0; off >>= 1) v += __shfl_xor(v, off);
      s[e] = v;
    }
    if (lane == 0) {
      float sc[NE];
#pragma unroll
      for (int e = 0; e < NE; e++) sc[e] = 1.f / (1.f + expf(-(s[e] + lb[e])));
      int i1 = 0;
#pragma unroll
      for (int e = 1; e < NE; e++)
        if (sc[e] > sc[i1]) i1 = e;  // ties -> lowest index (lax.top_k)
      int i2 = -1;
#pragma unroll
      for (int e = 0; e < NE; e++) {
        if (e == i1) continue;
        if (i2 < 0 || sc[e] > sc[i2]) i2 = e;
      }
      float w1 = sc[i1], w2 = sc[i2];
      float inv = 1.f / (w1 + w2 + 1e-8f);
      topi[t] = make_int2(i1, i2);
      topw[t] = make_float2(w1 * inv, w2 * inv);
    }
  }
}

// ---- build: 8 blocks (one per expert), fixed slot regions, no atomics ----
__global__ __launch_bounds__(256) void build_kernel(
    const int2* __restrict__ topi, const float2* __restrict__ topw,
    int* __restrict__ cnt, float* __restrict__ wm, int* __restrict__ lists) {
  const int e = blockIdx.x;
  const int wave = threadIdx.x >> 6, lane = threadIdx.x & 63;
  __shared__ int wc[4];
  __shared__ float wf[4];
  const int tbeg = wave * (NT / 4), tend = tbeg + NT / 4;

  int c = 0;
  float wa = 0.f;
  for (int t0 = tbeg; t0 < tend; t0 += 64) {
    int2 ti = topi[t0 + lane];
    float2 tw = topw[t0 + lane];
    bool hit = (ti.x == e) || (ti.y == e);
    float w = (ti.x == e) ? tw.x : ((ti.y == e) ? tw.y : 0.f);
    c += __popcll(__ballot(hit));
#pragma unroll
    for (int off = 32; off > 0; off >>= 1) w += __shfl_xor(w, off);
    wa += w;
  }
  if (lane == 0) { wc[wave] = c; wf[wave] = wa; }
  __syncthreads();
  int pos = 0;
  for (int w = 0; w < wave; w++) pos += wc[w];
  for (int t0 = tbeg; t0 < tend; t0 += 64) {
    int t = t0 + lane;
    int2 ti = topi[t];
    bool hit = (ti.x == e) || (ti.y == e);
    unsigned long long m = __ballot(hit);
    int pre = __popcll(m & ((1ull << lane) - 1ull));
    if (hit) lists[e * NT + pos + pre] = t;
    pos += __popcll(m);
  }
  if (threadIdx.x == 0) {
    int ctot = wc[0] + wc[1] + wc[2] + wc[3];
    cnt[e] = ctot;
    wm[e] = (wf[0] + wf[1] + wf[2] + wf[3]) / (float)(ctot > 0 ? ctot : 1);
  }
}

// ---- gate+up GEMM: 64x128 tile (M=64), glds16+swizzle, interleaved B.
// grid (16 ct, 32 rt, 9), ct FASTEST (A-tile shared by consecutive blocks).
__global__ __launch_bounds__(256, 4) void gemm_gu(
    const bf16* __restrict__ wb, const bf16* __restrict__ xb,
    const int* __restrict__ cnt, const int* __restrict__ lists,
    bf16* __restrict__ act_e, bf16* __restrict__ act_s) {
  const int z = blockIdx.z, ct = blockIdx.x, rt = blockIdx.y;
  const int tid = threadIdx.x;
  __shared__ int rows_s[64];
  __shared__ __align__(16) bf16 As[64 * 64];
  __shared__ __align__(16) bf16 Bs[128 * 64];
  int mrem, ldc;
  bf16* Cb;
  const bf16* Bb;
  if (z < NE) {
    if (ct >= 8) return;
    int c = cnt[z];
    if (rt * 64 >= c) return;
    mrem = c - rt * 64;
    if (tid < 64)
      rows_s[tid] = lists[z * NT + rt * 64 + (tid < mrem ? tid : mrem - 1)];
    Bb = wb + W_GU + ((size_t)z << 20) + (size_t)ct * 128 * H_DIM;
    Cb = act_e + ((size_t)z * NT + rt * 64) * I_DIM;
    ldc = I_DIM;
  } else {
    mrem = 64;
    if (tid < 64) rows_s[tid] = rt * 64 + tid;
    Bb = wb + W_SGU + (size_t)ct * 128 * H_DIM;
    Cb = act_s + (size_t)rt * 64 * SI_DIM;
    ldc = SI_DIM;
  }
  __syncthreads();

  const int lane = tid & 63, wave = tid >> 6;
  const int mw = (wave & 1) * 32, nw = (wave >> 1) * 64;
  const int l15 = lane & 15, quad = lane >> 4;
  const int srow = tid >> 3;   // 0..31
  const int cch = tid & 7;     // 16B chunk id
  const int p8 = cch * 8;
  const int sx = (l15 & 7) * 8;

  const bf16 *ap[2], *bp[4];
  int alo[2], blo[4];
#pragma unroll
  for (int r = 0; r < 2; r++) {
    int R = srow + r * 32;
    int gs = (cch ^ (R & 7)) * 8;
    ap[r] = xb + (size_t)rows_s[R] * H_DIM + gs;
    alo[r] = R * 64 + p8;
  }
#pragma unroll
  for (int r = 0; r < 4; r++) {
    int R = srow + r * 32;
    int gs = (cch ^ (R & 7)) * 8;
    bp[r] = Bb + (size_t)R * H_DIM + gs;
    blo[r] = R * 64 + p8;
  }

  f32x4 acc[2][4] = {};
  for (int k0 = 0; k0 < H_DIM; k0 += 64) {
#pragma unroll
    for (int r = 0; r < 2; r++) glds16(ap[r] + k0, &As[alo[r]]);
#pragma unroll
    for (int r = 0; r < 4; r++) glds16(bp[r] + k0, &Bs[blo[r]]);
    __syncthreads();
#pragma unroll
    for (int kk = 0; kk < 2; kk++) {
      const int ko = (kk * 4 + quad) * 8;
      bf16x8 av[2], bv[4];
#pragma unroll
      for (int i = 0; i < 2; i++)
        av[i] = *(const bf16x8*)&As[(mw + i * 16 + l15) * 64 + (ko ^ sx)];
#pragma unroll
      for (int j = 0; j < 4; j++)
        bv[j] = *(const bf16x8*)&Bs[(nw + j * 16 + l15) * 64 + (ko ^ sx)];
#pragma unroll
      for (int i = 0; i < 2; i++)
#pragma unroll
        for (int j = 0; j < 4; j++)
          acc[i][j] = __builtin_amdgcn_mfma_f32_16x16x32_bf16(av[i], bv[j], acc[i][j], 0, 0, 0);
    }
    __syncthreads();
  }

  // j even = gate, j odd = up (adjacent 16-col groups, same lane/reg)
#pragma unroll
  for (int i = 0; i < 2; i++) {
#pragma unroll
    for (int rg = 0; rg < 4; rg++) {
      int rl = mw + i * 16 + quad * 4 + rg;
      if (rl < mrem) {
#pragma unroll
        for (int jp = 0; jp < 2; jp++) {
          float g = acc[i][jp * 2][rg];
          float u = acc[i][jp * 2 + 1][rg];
          int c = ct * 64 + (nw >> 1) + jp * 16 + l15;
          Cb[(size_t)rl * ldc + c] = (bf16)((g / (1.f + __expf(-g))) * u);
        }
      }
    }
  }
}

// ---- down GEMM: 64x128 tile, glds16+swizzle; atomicAdd(out, wm*y).
// grid (8 ct, 32 rt, 9), ct fastest.
__global__ __launch_bounds__(256, 4) void gemm_down(
    const bf16* __restrict__ wb, const bf16* __restrict__ act_e,
    const bf16* __restrict__ act_s, const int* __restrict__ cnt,
    const float* __restrict__ wm, const int* __restrict__ lists,
    float* __restrict__ out) {
  const int z = blockIdx.z, ct = blockIdx.x, rt = blockIdx.y;
  const int tid = threadIdx.x;
  __shared__ int rows_s[64];
  __shared__ __align__(16) bf16 As[64 * 64];
  __shared__ __align__(16) bf16 Bs[128 * 64];
  int K, mrem;
  const bf16 *Ab, *Bb;
  if (z < NE) {
    int c = cnt[z];
    if (rt * 64 >= c) return;
    mrem = c - rt * 64;
    if (tid < 64)
      rows_s[tid] = lists[z * NT + rt * 64 + (tid < mrem ? tid : mrem - 1)];
    Ab = act_e + ((size_t)z * NT + rt * 64) * I_DIM;
    K = I_DIM;
    Bb = wb + W_DN + ((size_t)z << 19) + (size_t)ct * 128 * I_DIM;
  } else {
    mrem = 64;
    if (tid < 64) rows_s[tid] = rt * 64 + tid;
    Ab = act_s + (size_t)rt * 64 * SI_DIM;
    K = SI_DIM;
    Bb = wb + W_SDN + (size_t)ct * 128 * SI_DIM;
  }
  __syncthreads();

  const int lane = tid & 63, wave = tid >> 6;
  const int mw = (wave & 1) * 32, nw = (wave >> 1) * 64;
  const int l15 = lane & 15, quad = lane >> 4;
  const int srow = tid >> 3;
  const int cch = tid & 7;
  const int p8 = cch * 8;
  const int sx = (l15 & 7) * 8;

  const bf16 *ap[2], *bp[4];
  int alo[2], blo[4];
#pragma unroll
  for (int r = 0; r < 2; r++) {
    int R = srow + r * 32;
    int gs = (cch ^ (R & 7)) * 8;
    ap[r] = Ab + (size_t)R * K + gs;
    alo[r] = R * 64 + p8;
  }
#pragma unroll
  for (int r = 0; r < 4; r++) {
    int R = srow + r * 32;
    int gs = (cch ^ (R & 7)) * 8;
    bp[r] = Bb + (size_t)R * K + gs;
    blo[r] = R * 64 + p8;
  }

  f32x4 acc[2][4] = {};
  for (int k0 = 0; k0 < K; k0 += 64) {
#pragma unroll
    for (int r = 0; r < 2; r++) glds16(ap[r] + k0, &As[alo[r]]);
#pragma unroll
    for (int r = 0; r < 4; r++) glds16(bp[r] + k0, &Bs[blo[r]]);
    __syncthreads();
#pragma unroll
    for (int kk = 0; kk < 2; kk++) {
      const int ko = (kk * 4 + quad) * 8;
      bf16x8 av[2], bv[4];
#pragma unroll
      for (int i = 0; i < 2; i++)
        av[i] = *(const bf16x8*)&As[(mw + i * 16 + l15) * 64 + (ko ^ sx)];
#pragma unroll
      for (int j = 0; j < 4; j++)
        bv[j] = *(const bf16x8*)&Bs[(nw + j * 16 + l15) * 64 + (ko ^ sx)];
#pragma unroll
      for (int i = 0; i < 2; i++)
#pragma unroll
        for (int j = 0; j < 4; j++)
          acc[i][j] = __builtin_amdgcn_mfma_f32_16x16x32_bf16(av[i], bv[j], acc[i][j], 0, 0, 0);
    }
    __syncthreads();
  }

  const float wsc = (z < NE) ? wm[z] : 1.f;
#pragma unroll
  for (int i = 0; i < 2; i++) {
#pragma unroll
    for (int rg = 0; rg < 4; rg++) {
      int rl = mw + i * 16 + quad * 4 + rg;
      if (rl < mrem) {
        int t = rows_s[rl];
        float* orow = out + (size_t)t * H_DIM + ct * 128 + nw;
#pragma unroll
        for (int j = 0; j < 4; j++)
          atomicAdd(&orow[j * 16 + l15], wsc * acc[i][j][rg]);
      }
    }
  }
}

extern "C" void kernel_launch(void* const* d_in, const int* in_sizes, int n_in,
                              void* d_out, int out_size, void* d_ws,
                              size_t ws_size, hipStream_t stream) {
  (void)in_sizes; (void)n_in; (void)out_size; (void)ws_size;
  const float* x  = (const float*)d_in[0];
  const float* gw = (const float*)d_in[1];
  const float* lb = (const float*)d_in[2];
  const float* eg = (const float*)d_in[3];
  const float* eu = (const float*)d_in[4];
  const float* ed = (const float*)d_in[5];
  const float* sg = (const float*)d_in[6];
  const float* su = (const float*)d_in[7];
  const float* sd = (const float*)d_in[8];
  float* out = (float*)d_out;
  char* ws = (char*)d_ws;

  int* cnt     = (int*)(ws + OFF_CNT);
  float* wm    = (float*)(ws + OFF_WM);
  int2* topi   = (int2*)(ws + OFF_TOPI);
  float2* topw = (float2*)(ws + OFF_TOPW);
  int* lists   = (int*)(ws + OFF_LISTS);
  bf16* wb     = (bf16*)(ws + OFF_WB);
  bf16* xb     = (bf16*)(ws + OFF_XB);
  bf16* act_e  = (bf16*)(ws + OFF_ACTE);
  bf16* act_s  = (bf16*)(ws + OFF_ACTS);

  hipMemsetAsync(d_out, 0, (size_t)NT * H_DIM * sizeof(float), stream);
  prep_kernel<<<NWB + NRB, 256, 0, stream>>>(x, gw, lb, eg, eu, ed, sg, su, sd,
                                             wb, xb, topi, topw);
  build_kernel<<<NE, 256, 0, stream>>>(topi, topw, cnt, wm, lists);
  gemm_gu<<<dim3(16, 32, 9), 256, 0, stream>>>(wb, xb, cnt, lists, act_e,
                                               act_s);
  gemm_down<<<dim3(8, 32, 9), 256, 0, stream>>>(wb, act_e, act_s, cnt, wm,
                                                lists, out);
}